// Round 3
// baseline (488.203 us; speedup 1.0000x reference)
//
#include <hip/hip_runtime.h>
#include <math.h>

#define N 2048
#define E 65536
#define EMBED 64
#define H 128
#define NT 20
#define C3 320   /* EMBED + H + H */
#define CAP 96   /* bucket capacity; Poisson(32) degrees, max ~60 */
#define SLOPE 0.01f
#define NBLK 1024
#define NTHR 256

__device__ __forceinline__ float leaky(float x) { return x > 0.f ? x : SLOPE * x; }

__device__ __forceinline__ float wave_sum(float v) {
#pragma unroll
    for (int o = 32; o > 0; o >>= 1) v += __shfl_xor(v, o, 64);
    return v;
}

// Software grid barrier. Co-residency of all 1024 blocks is guaranteed by
// capacity arithmetic: 256 thr/block (4 waves), LDS ~5.7 KB -> even at the
// 512-VGPR worst case each CU holds >=4 blocks, so 256 CUs hold >=1024.
// Release fence -> writeback producer XCD L2; acquire -> invalidate L1/L2.
__device__ __forceinline__ void grid_sync(int* bar, int target) {
    __syncthreads();
    if (threadIdx.x == 0) {
        __builtin_amdgcn_fence(__ATOMIC_RELEASE, "agent");
        __hip_atomic_fetch_add(bar, 1, __ATOMIC_RELAXED, __HIP_MEMORY_SCOPE_AGENT);
        while (__hip_atomic_load(bar, __ATOMIC_RELAXED, __HIP_MEMORY_SCOPE_AGENT) < target)
            __builtin_amdgcn_s_sleep(2);
        __builtin_amdgcn_fence(__ATOMIC_ACQUIRE, "agent");
    }
    __syncthreads();
}

// ====== gate partial: one wave, alternate 8-edge batches starting at i0start, step 16 ======
__device__ __forceinline__ void gate_partial(
    int dst, int lane, float xr,
    const float* __restrict__ A,
    float w0, float w1, float attl0, float attl1,
    const int* __restrict__ srcs, const float* __restrict__ eas, int cnt, int i0start,
    float& m_out, float& s_out, float& v0_out, float& v1_out) {
    int c0 = 2 * lane;
    int base = dst * CAP;
    float mmax = -INFINITY, s = 0.f, v0 = 0.f, v1 = 0.f;
    for (int i0 = i0start; i0 < cnt; i0 += 16) {
        int nb = cnt - i0; if (nb > 8) nb = 8;
        float h0[8], h1v[8], p[8];
#pragma unroll
        for (int e = 0; e < 8; e++) {
            float ea = 0.f; float2 av = make_float2(0.f, 0.f);
            if (e < nb) {
                int sn = srcs[base + i0 + e];
                ea = eas[base + i0 + e];
                av = *(const float2*)&A[sn * H + c0];
            }
            h0[e] = leaky(fmaf(w0, ea, av.x));
            h1v[e] = leaky(fmaf(w1, ea, av.y));
            p[e] = h0[e] * attl0 + h1v[e] * attl1;
        }
#pragma unroll
        for (int o = 32; o > 0; o >>= 1) {
#pragma unroll
            for (int e = 0; e < 8; e++) p[e] += __shfl_xor(p[e], o, 64);
        }
        float alpha[8];
#pragma unroll
        for (int e = 0; e < 8; e++)
            alpha[e] = (e < nb) ? leaky(p[e] + xr) : -INFINITY;
        float mb = alpha[0];
#pragma unroll
        for (int e = 1; e < 8; e++) mb = fmaxf(mb, alpha[e]);
        float mnew = fmaxf(mmax, mb);
        float scale = __expf(mmax - mnew);  // first batch: exp(-inf)=0
        float sw = 0.f, sv0 = 0.f, sv1 = 0.f;
#pragma unroll
        for (int e = 0; e < 8; e++) {
            float we = __expf(alpha[e] - mnew);  // invalid lanes -> 0
            sw += we;
            sv0 = fmaf(we, h0[e], sv0);
            sv1 = fmaf(we, h1v[e], sv1);
        }
        s = fmaf(s, scale, sw);
        v0 = fmaf(v0, scale, sv0);
        v1 = fmaf(v1, scale, sv1);
        mmax = mnew;
    }
    m_out = mmax; s_out = s; v0_out = v0; v1_out = v1;
}

__device__ __forceinline__ void gate_merge(
    float mA, float sA, float vA0, float vA1,
    float mB, float sB, float vB0, float vB1,
    float& o0, float& o1) {
    float m = fmaxf(mA, mB);
    if (m == -INFINITY) { o0 = 0.f; o1 = 0.f; return; }
    float eA = __expf(mA - m), eB = __expf(mB - m);  // exp(-inf)=0 for empty side
    float inv = 1.f / (fmaf(sA, eA, sB * eB) + 1e-16f);
    o0 = fmaf(vA0, eA, vB0 * eB) * inv;
    o1 = fmaf(vA1, eA, vB1 * eB) * inv;
}

// ========== single fused kernel: 1024 blocks x 256 threads, 3 grid barriers ==========
__global__ __launch_bounds__(NTHR) void k_fused(
    const int* __restrict__ ids, const int* __restrict__ ei,
    const float* __restrict__ eattr, const float* __restrict__ mmat,
    const float* __restrict__ emb,
    const float* __restrict__ l0_lin1, const float* __restrict__ l0_lin2,
    const float* __restrict__ l0_att_l, const float* __restrict__ l0_att_r,
    const float* __restrict__ l0_bias,
    const float* __restrict__ l1_lin1, const float* __restrict__ l1_lin2,
    const float* __restrict__ l1_att_l, const float* __restrict__ l1_att_r,
    const float* __restrict__ l1_bias,
    const float* __restrict__ W1, const float* __restrict__ b1,
    const float* __restrict__ W2, const float* __restrict__ b2,
    int* __restrict__ cursor, int* __restrict__ bar,
    int* __restrict__ srcs, float* __restrict__ eas,
    float* __restrict__ x, float* __restrict__ A0, float* __restrict__ A1,
    float* __restrict__ h1, float* __restrict__ aArr, float* __restrict__ bT,
    float* __restrict__ WT1, float* __restrict__ LT0, float* __restrict__ LT1,
    float* __restrict__ out) {
    __shared__ float vs[4][H];
    __shared__ float pm[4], ps[4];
    __shared__ float agg_s[2][H];
    __shared__ float big[2][C3];   // P1: hs (first 2*H); P2: feat
    __shared__ float red[8];
    const int b = blockIdx.x;
    const int tid = threadIdx.x;
    const int gtid = b * NTHR + tid;   // 0..262143

    // ---------------- P0: scatter + transposes + x gather + A0 ----------------
    if (gtid < E) {                       // scatter (atomic bucketing by dst)
        int d = ei[E + gtid];
        int pos = atomicAdd(&cursor[d], 1);
        if (pos < CAP) {
            srcs[d * CAP + pos] = ei[gtid];
            eas[d * CAP + pos] = eattr[gtid];
        }
    }
    if (gtid < 16384) {                   // WT1 = l1_lin1[:, :H]^T
        WT1[gtid] = l1_lin1[(gtid & 127) * (H + 1) + (gtid >> 7)];
    } else if (gtid < 32768) {            // LT0 = l0_lin2^T
        int j = gtid - 16384;
        LT0[j] = l0_lin2[(j & 127) * H + (j >> 7)];
    } else if (gtid < 49152) {            // LT1 = l1_lin2^T
        int j = gtid - 32768;
        LT1[j] = l1_lin2[(j & 127) * H + (j >> 7)];
    }
    if (gtid < N * EMBED) {               // x gather (first half of grid threads)
        int g = gtid >> 6, c = gtid & 63;
        x[gtid] = emb[ids[g] * EMBED + c];
    }
    {   // lin0: A0 rows for nodes b*2, b*2+1 (weights via L1-cached row reads)
        int n0 = b * 2;
        int k = tid & 127, q = tid >> 7;
        int nn = __builtin_amdgcn_readfirstlane(n0 + q);
        const float* xr = emb + (size_t)ids[nn] * EMBED;
        const float* wr = l0_lin1 + k * (EMBED + 1);
        float acc = 0.f;
#pragma unroll 4
        for (int c = 0; c < EMBED; c++)
            acc = fmaf(xr[c], wr[c], acc);
        A0[(n0 + q) * H + k] = acc;
    }
    grid_sync(bar, NBLK);

    // ---------------- P1: gate0 (2 dsts, 2 waves/dst) + lin1 ----------------
    {
        float (*hs)[H] = (float(*)[H])big;
        int n0 = b * 2;
        int wv = __builtin_amdgcn_readfirstlane(tid >> 6);  // 0..3
        int lane = tid & 63;
        int c0 = 2 * lane;
        int p = wv >> 1, h = wv & 1;
        int dst = n0 + p;

        float xr = wave_sum(x[dst * EMBED + lane] * l0_att_r[lane]);
        float attl0 = l0_att_l[c0], attl1 = l0_att_l[c0 + 1];
        float w0 = l0_lin1[c0 * (EMBED + 1) + EMBED];
        float w1 = l0_lin1[(c0 + 1) * (EMBED + 1) + EMBED];
        int cnt = cursor[dst]; if (cnt > CAP) cnt = CAP;

        float pm_, ps_, pv0, pv1;
        gate_partial(dst, lane, xr, A0, w0, w1, attl0, attl1, srcs, eas, cnt, h * 8,
                     pm_, ps_, pv0, pv1);
        vs[wv][c0] = pv0; vs[wv][c0 + 1] = pv1;
        if (lane == 0) { pm[wv] = pm_; ps[wv] = ps_; }
        __syncthreads();
        if (h == 0) {
            float o0, o1;
            gate_merge(pm_, ps_, pv0, pv1,
                       pm[wv ^ 1], ps[wv ^ 1], vs[wv ^ 1][c0], vs[wv ^ 1][c0 + 1], o0, o1);
            agg_s[p][c0] = o0;
            agg_s[p][c0 + 1] = o1;
        }
        __syncthreads();

        // h1 = relu(agg @ LT0 + b0)
        int k = tid & 127, q = tid >> 7;
        float acc0 = l0_bias[k];
#pragma unroll 2
        for (int ct = 0; ct < H / 4; ct++) {
            float u0 = LT0[(4 * ct + 0) * H + k];
            float u1 = LT0[(4 * ct + 1) * H + k];
            float u2 = LT0[(4 * ct + 2) * H + k];
            float u3 = LT0[(4 * ct + 3) * H + k];
            float4 f0 = *(const float4*)&agg_s[q][4 * ct];
            acc0 = fmaf(f0.x, u0, acc0); acc0 = fmaf(f0.y, u1, acc0);
            acc0 = fmaf(f0.z, u2, acc0); acc0 = fmaf(f0.w, u3, acc0);
        }
        float hv0 = fmaxf(acc0, 0.f);
        h1[(n0 + q) * H + k] = hv0;
        hs[q][k] = hv0;
        __syncthreads();

        // A1 = h1 @ WT1
        float a0 = 0.f;
#pragma unroll 2
        for (int ct = 0; ct < H / 4; ct++) {
            float u0 = WT1[(4 * ct + 0) * H + k];
            float u1 = WT1[(4 * ct + 1) * H + k];
            float u2 = WT1[(4 * ct + 2) * H + k];
            float u3 = WT1[(4 * ct + 3) * H + k];
            float4 f0 = *(const float4*)&hs[q][4 * ct];
            a0 = fmaf(f0.x, u0, a0); a0 = fmaf(f0.y, u1, a0);
            a0 = fmaf(f0.z, u2, a0); a0 = fmaf(f0.w, u3, a0);
        }
        A1[(n0 + q) * H + k] = a0;
    }
    grid_sync(bar, 2 * NBLK);

    // ---------------- P2: gate1 (2 dsts, 2 waves/dst) + tail ----------------
    {
        float (*feat)[C3] = big;   // [0..63]=x, [64..191]=h1, [192..319]=h2
        int n0 = b * 2;
        int wv = __builtin_amdgcn_readfirstlane(tid >> 6);
        int lane = tid & 63;
        int c0 = 2 * lane;
        int p = wv >> 1, h = wv & 1;
        int dst = n0 + p;

        float xr = wave_sum(h1[dst * H + lane] * l1_att_r[lane] +
                            h1[dst * H + 64 + lane] * l1_att_r[64 + lane]);
        float attl0 = l1_att_l[c0], attl1 = l1_att_l[c0 + 1];
        float w0 = l1_lin1[c0 * (H + 1) + H];
        float w1 = l1_lin1[(c0 + 1) * (H + 1) + H];
        int cnt = cursor[dst]; if (cnt > CAP) cnt = CAP;

        float pm_, ps_, pv0, pv1;
        gate_partial(dst, lane, xr, A1, w0, w1, attl0, attl1, srcs, eas, cnt, h * 8,
                     pm_, ps_, pv0, pv1);
        vs[wv][c0] = pv0; vs[wv][c0 + 1] = pv1;
        if (lane == 0) { pm[wv] = pm_; ps[wv] = ps_; }
        __syncthreads();
        if (h == 0) {
            float o0, o1;
            gate_merge(pm_, ps_, pv0, pv1,
                       pm[wv ^ 1], ps[wv ^ 1], vs[wv ^ 1][c0], vs[wv ^ 1][c0 + 1], o0, o1);
            agg_s[p][c0] = o0;
            agg_s[p][c0 + 1] = o1;
        }

        for (int idx = tid; idx < 2 * EMBED; idx += NTHR) {
            int g = idx >> 6, c = idx & 63;
            feat[g][c] = x[(n0 + g) * EMBED + c];
        }
        for (int idx = tid; idx < 2 * H; idx += NTHR) {
            int g = idx >> 7, c = idx & 127;
            feat[g][EMBED + c] = h1[(n0 + g) * H + c];
        }
        __syncthreads();

        // h2 = relu(agg @ LT1 + bL1)
        int k = tid & 127, q = tid >> 7;
        float acc0 = l1_bias[k];
#pragma unroll 2
        for (int ct = 0; ct < H / 4; ct++) {
            float u0 = LT1[(4 * ct + 0) * H + k];
            float u1 = LT1[(4 * ct + 1) * H + k];
            float u2 = LT1[(4 * ct + 2) * H + k];
            float u3 = LT1[(4 * ct + 3) * H + k];
            float4 f0 = *(const float4*)&agg_s[q][4 * ct];
            acc0 = fmaf(f0.x, u0, acc0); acc0 = fmaf(f0.y, u1, acc0);
            acc0 = fmaf(f0.z, u2, acc0); acc0 = fmaf(f0.w, u3, acc0);
        }
        feat[q][EMBED + H + k] = fmaxf(acc0, 0.f);
        __syncthreads();

        // 80 outputs: o = g*40 + side*20 + t
        if (tid < 80) {
            int g = tid / 40, u = tid % 40;
            int t = u % 20, side = u / 20;
            const float* wrow = W1 + t * (2 * C3) + side * C3;
            float s = 0.f;
#pragma unroll 4
            for (int ct = 0; ct < C3 / 4; ct++) {
                float4 fv = *(const float4*)&feat[g][4 * ct];
                float4 wv4 = *(const float4*)&wrow[4 * ct];
                s = fmaf(fv.x, wv4.x, s);
                s = fmaf(fv.y, wv4.y, s);
                s = fmaf(fv.z, wv4.z, s);
                s = fmaf(fv.w, wv4.w, s);
            }
            if (side == 0) aArr[(n0 + g) * NT + t] = s;
            else bT[t * N + (n0 + g)] = s;
        }
    }
    grid_sync(bar, 3 * NBLK);

    // ---------------- P3: logits + row softmax (2 rows/block) ----------------
    {
        int i0 = b * 2;
        int lane = tid & 63, wv = tid >> 6;
        float w2r[NT];
#pragma unroll
        for (int t = 0; t < NT; t++) w2r[t] = W2[t];
        float b2v = b2[0];
        float ab[2][NT];
#pragma unroll
        for (int g = 0; g < 2; g++) {
#pragma unroll
            for (int t = 0; t < NT; t++)
                ab[g][t] = aArr[(i0 + g) * NT + t] + b1[t];
        }
        float4 l4[2][2];
        float tmax[2] = {-INFINITY, -INFINITY};
#pragma unroll
        for (int it = 0; it < 2; it++) {
            int j = 4 * tid + 1024 * it;
            float4 s4[2];
#pragma unroll
            for (int g = 0; g < 2; g++) s4[g] = make_float4(b2v, b2v, b2v, b2v);
#pragma unroll
            for (int t = 0; t < NT; t++) {
                float4 bt4 = *(const float4*)&bT[t * N + j];
#pragma unroll
                for (int g = 0; g < 2; g++) {
                    float a = ab[g][t], w = w2r[t];
                    s4[g].x = fmaf(fmaxf(a + bt4.x, 0.f), w, s4[g].x);
                    s4[g].y = fmaf(fmaxf(a + bt4.y, 0.f), w, s4[g].y);
                    s4[g].z = fmaf(fmaxf(a + bt4.z, 0.f), w, s4[g].z);
                    s4[g].w = fmaf(fmaxf(a + bt4.w, 0.f), w, s4[g].w);
                }
            }
#pragma unroll
            for (int g = 0; g < 2; g++) {
                float4 mm = *(const float4*)&mmat[(size_t)(i0 + g) * N + j];
                s4[g].x *= mm.x; s4[g].y *= mm.y; s4[g].z *= mm.z; s4[g].w *= mm.w;
                l4[g][it] = s4[g];
                tmax[g] = fmaxf(tmax[g], fmaxf(fmaxf(s4[g].x, s4[g].y), fmaxf(s4[g].z, s4[g].w)));
            }
        }
#pragma unroll
        for (int g = 0; g < 2; g++) {
#pragma unroll
            for (int o = 32; o > 0; o >>= 1)
                tmax[g] = fmaxf(tmax[g], __shfl_xor(tmax[g], o, 64));
        }
        if (lane == 0) {
#pragma unroll
            for (int g = 0; g < 2; g++) red[wv * 2 + g] = tmax[g];
        }
        __syncthreads();
        float mfin[2];
#pragma unroll
        for (int g = 0; g < 2; g++)
            mfin[g] = fmaxf(fmaxf(red[g], red[2 + g]), fmaxf(red[4 + g], red[6 + g]));
        __syncthreads();

        float ts[2] = {0.f, 0.f};
#pragma unroll
        for (int it = 0; it < 2; it++) {
#pragma unroll
            for (int g = 0; g < 2; g++) {
                float4 v = l4[g][it];
                v.x = __expf(v.x - mfin[g]);
                v.y = __expf(v.y - mfin[g]);
                v.z = __expf(v.z - mfin[g]);
                v.w = __expf(v.w - mfin[g]);
                l4[g][it] = v;
                ts[g] += v.x + v.y + v.z + v.w;
            }
        }
#pragma unroll
        for (int g = 0; g < 2; g++) {
#pragma unroll
            for (int o = 32; o > 0; o >>= 1) ts[g] += __shfl_xor(ts[g], o, 64);
        }
        if (lane == 0) {
#pragma unroll
            for (int g = 0; g < 2; g++) red[wv * 2 + g] = ts[g];
        }
        __syncthreads();
        float inv[2];
#pragma unroll
        for (int g = 0; g < 2; g++)
            inv[g] = 1.f / (red[g] + red[2 + g] + red[4 + g] + red[6 + g]);

#pragma unroll
        for (int it = 0; it < 2; it++) {
            int j = 4 * tid + 1024 * it;
#pragma unroll
            for (int g = 0; g < 2; g++) {
                float4 v = l4[g][it];
                v.x *= inv[g]; v.y *= inv[g]; v.z *= inv[g]; v.w *= inv[g];
                *(float4*)&out[(size_t)(i0 + g) * N + j] = v;
            }
        }
    }
}

extern "C" void kernel_launch(void* const* d_in, const int* in_sizes, int n_in,
                              void* d_out, int out_size, void* d_ws, size_t ws_size,
                              hipStream_t stream) {
    const int*   node_ids = (const int*)d_in[0];
    const int*   ei       = (const int*)d_in[1];   // [2][E]: row0 = src, row1 = dst
    const float* eattr    = (const float*)d_in[2];
    const float* mmat     = (const float*)d_in[3];
    const float* emb      = (const float*)d_in[4];
    const float* l0_lin1  = (const float*)d_in[5];
    const float* l0_lin2  = (const float*)d_in[6];
    const float* l0_att_l = (const float*)d_in[7];
    const float* l0_att_r = (const float*)d_in[8];
    const float* l0_bias  = (const float*)d_in[9];
    const float* l1_lin1  = (const float*)d_in[10];
    const float* l1_lin2  = (const float*)d_in[11];
    const float* l1_att_l = (const float*)d_in[12];
    const float* l1_att_r = (const float*)d_in[13];
    const float* l1_bias  = (const float*)d_in[14];
    const float* W1       = (const float*)d_in[15];
    const float* b1       = (const float*)d_in[16];
    const float* W2       = (const float*)d_in[17];
    const float* b2       = (const float*)d_in[18];
    float* out = (float*)d_out;

    char* w = (char*)d_ws;
    auto alloc = [&](size_t bytes) {
        char* p = w;
        w += (bytes + 255) & ~(size_t)255;
        return p;
    };
    int*   cursor = (int*)alloc((N + 64) * sizeof(int));  // cursor[N] then barrier counter
    int*   bar    = cursor + N;
    int*   srcs   = (int*)alloc(N * CAP * sizeof(int));
    float* eas    = (float*)alloc(N * CAP * sizeof(float));
    float* x      = (float*)alloc(N * EMBED * sizeof(float));
    float* A0     = (float*)alloc(N * H * sizeof(float));
    float* A1     = (float*)alloc(N * H * sizeof(float));
    float* h1     = (float*)alloc(N * H * sizeof(float));
    float* aArr   = (float*)alloc(N * NT * sizeof(float));
    float* bT     = (float*)alloc(NT * N * sizeof(float));
    float* WT1    = (float*)alloc(H * H * sizeof(float));
    float* LT0    = (float*)alloc(H * H * sizeof(float));
    float* LT1    = (float*)alloc(H * H * sizeof(float));

    hipMemsetAsync(cursor, 0, (N + 64) * sizeof(int), stream);

    k_fused<<<NBLK, NTHR, 0, stream>>>(node_ids, ei, eattr, mmat, emb,
                                       l0_lin1, l0_lin2, l0_att_l, l0_att_r, l0_bias,
                                       l1_lin1, l1_lin2, l1_att_l, l1_att_r, l1_bias,
                                       W1, b1, W2, b2,
                                       cursor, bar, srcs, eas, x, A0, A1, h1,
                                       aArr, bT, WT1, LT0, LT1, out);
}

// Round 4
// 216.728 us; speedup vs baseline: 2.2526x; 2.2526x over previous
//
#include <hip/hip_runtime.h>
#include <math.h>

#define N 2048
#define E 65536
#define EMBED 64
#define H 128
#define NT 20
#define C3 320   /* EMBED + H + H */
#define CAP 96   /* bucket capacity; Poisson(32) degrees, max ~60 */
#define SLOPE 0.01f
#define NBLK 256
#define NTHR 1024

__device__ __forceinline__ float leaky(float x) { return x > 0.f ? x : SLOPE * x; }

__device__ __forceinline__ float wave_sum(float v) {
#pragma unroll
    for (int o = 32; o > 0; o >>= 1) v += __shfl_xor(v, o, 64);
    return v;
}

// Contention-engineered grid barrier for 256 co-resident blocks.
// 8 counter cache-lines (block b arrives at line b&7 -> 32 serialized RMWs per
// line, parallel across lines ~ few us, not 256 serialized on one line).
// Pollers: one thread per block, s_sleep(32) ~ 2k cycles cadence -> ~2M loads/s
// total (vs round-3's ~1e9/s single-line hammering). Monotonic targets.
// Release fence before arrival publishes this block's stores; acquire after
// the count is reached invalidates local caches (cross-XCD safety).
__device__ __forceinline__ void grid_sync(int* ctr, int target, int b) {
    __syncthreads();
    if (threadIdx.x == 0) {
        __builtin_amdgcn_fence(__ATOMIC_RELEASE, "agent");
        __hip_atomic_fetch_add(&ctr[(b & 7) << 6], 1, __ATOMIC_RELAXED,
                               __HIP_MEMORY_SCOPE_AGENT);
        for (;;) {
            int sum = 0;
#pragma unroll
            for (int i = 0; i < 8; i++)
                sum += __hip_atomic_load(&ctr[i << 6], __ATOMIC_RELAXED,
                                         __HIP_MEMORY_SCOPE_AGENT);
            if (sum >= target) break;
            __builtin_amdgcn_s_sleep(32);
        }
        __builtin_amdgcn_fence(__ATOMIC_ACQUIRE, "agent");
    }
    __syncthreads();
}

// ====== gate partial: one wave, alternate 8-edge batches starting at i0start, step 16 ======
__device__ __forceinline__ void gate_partial(
    int dst, int lane, float xr,
    const float* __restrict__ A,
    float w0, float w1, float attl0, float attl1,
    const int* __restrict__ srcs, const float* __restrict__ eas, int cnt, int i0start,
    float& m_out, float& s_out, float& v0_out, float& v1_out) {
    int c0 = 2 * lane;
    int base = dst * CAP;
    float mmax = -INFINITY, s = 0.f, v0 = 0.f, v1 = 0.f;
    for (int i0 = i0start; i0 < cnt; i0 += 16) {
        int nb = cnt - i0; if (nb > 8) nb = 8;
        float h0[8], h1v[8], p[8];
#pragma unroll
        for (int e = 0; e < 8; e++) {
            float ea = 0.f; float2 av = make_float2(0.f, 0.f);
            if (e < nb) {
                int sn = srcs[base + i0 + e];
                ea = eas[base + i0 + e];
                av = *(const float2*)&A[sn * H + c0];
            }
            h0[e] = leaky(fmaf(w0, ea, av.x));
            h1v[e] = leaky(fmaf(w1, ea, av.y));
            p[e] = h0[e] * attl0 + h1v[e] * attl1;
        }
#pragma unroll
        for (int o = 32; o > 0; o >>= 1) {
#pragma unroll
            for (int e = 0; e < 8; e++) p[e] += __shfl_xor(p[e], o, 64);
        }
        float alpha[8];
#pragma unroll
        for (int e = 0; e < 8; e++)
            alpha[e] = (e < nb) ? leaky(p[e] + xr) : -INFINITY;
        float mb = alpha[0];
#pragma unroll
        for (int e = 1; e < 8; e++) mb = fmaxf(mb, alpha[e]);
        float mnew = fmaxf(mmax, mb);
        float scale = __expf(mmax - mnew);  // first batch: exp(-inf)=0
        float sw = 0.f, sv0 = 0.f, sv1 = 0.f;
#pragma unroll
        for (int e = 0; e < 8; e++) {
            float we = __expf(alpha[e] - mnew);  // invalid lanes -> 0
            sw += we;
            sv0 = fmaf(we, h0[e], sv0);
            sv1 = fmaf(we, h1v[e], sv1);
        }
        s = fmaf(s, scale, sw);
        v0 = fmaf(v0, scale, sv0);
        v1 = fmaf(v1, scale, sv1);
        mmax = mnew;
    }
    m_out = mmax; s_out = s; v0_out = v0; v1_out = v1;
}

__device__ __forceinline__ void gate_merge(
    float mA, float sA, float vA0, float vA1,
    float mB, float sB, float vB0, float vB1,
    float& o0, float& o1) {
    float m = fmaxf(mA, mB);
    if (m == -INFINITY) { o0 = 0.f; o1 = 0.f; return; }
    float eA = __expf(mA - m), eB = __expf(mB - m);  // exp(-inf)=0 for empty side
    float inv = 1.f / (fmaf(sA, eA, sB * eB) + 1e-16f);
    o0 = fmaf(vA0, eA, vB0 * eB) * inv;
    o1 = fmaf(vA1, eA, vB1 * eB) * inv;
}

// ===== single fused kernel: 256 blocks x 1024 threads (16 waves/CU), 3 barriers =====
// Block b owns nodes 8b..8b+7 across ALL phases -> h1 and aArr live in LDS only.
__global__ __launch_bounds__(NTHR) void k_fused(
    const int* __restrict__ ids, const int* __restrict__ ei,
    const float* __restrict__ eattr, const float* __restrict__ mmat,
    const float* __restrict__ emb,
    const float* __restrict__ l0_lin1, const float* __restrict__ l0_lin2,
    const float* __restrict__ l0_att_l, const float* __restrict__ l0_att_r,
    const float* __restrict__ l0_bias,
    const float* __restrict__ l1_lin1, const float* __restrict__ l1_lin2,
    const float* __restrict__ l1_att_l, const float* __restrict__ l1_att_r,
    const float* __restrict__ l1_bias,
    const float* __restrict__ W1, const float* __restrict__ b1,
    const float* __restrict__ W2, const float* __restrict__ b2,
    int* __restrict__ cursor, int* __restrict__ bar,
    int* __restrict__ srcs, float* __restrict__ eas,
    float* __restrict__ x, float* __restrict__ A0, float* __restrict__ A1,
    float* __restrict__ bT,
    float* __restrict__ WT1, float* __restrict__ LT0, float* __restrict__ LT1,
    float* __restrict__ out) {
    // LDS layout (floats): vs[16][128] | pm[16] | ps[16] | agg[8][128] |
    //                      hs[8][128]  | feat[8][320] | aL[8][20]
    __shared__ float smem[2048 + 16 + 16 + 1024 + 1024 + 2560 + 160];
    float* vs   = smem;                 // [16][H]
    float* pm   = smem + 2048;          // [16]
    float* ps   = smem + 2064;          // [16]
    float* agg  = smem + 2080;          // [8][H]
    float* hs   = smem + 3104;          // [8][H]   (persists P1 -> P2)
    float* feat = smem + 4128;          // [8][C3]
    float* aL   = smem + 6688;          // [8][NT]  (persists P2 -> P3)
    const int b = blockIdx.x;
    const int tid = threadIdx.x;
    const int gtid = b * NTHR + tid;    // 0..262143
    const int n0 = b * 8;

    // ---------------- P0: scatter + transposes + x gather + A0 ----------------
    if (gtid < E) {                       // scatter (blocks 0..63)
        int d = ei[E + gtid];
        int pos = atomicAdd(&cursor[d], 1);
        if (pos < CAP) {
            srcs[d * CAP + pos] = ei[gtid];
            eas[d * CAP + pos] = eattr[gtid];
        }
    }
    if (gtid < 16384) {                   // WT1 = l1_lin1[:, :H]^T
        WT1[gtid] = l1_lin1[(gtid & 127) * (H + 1) + (gtid >> 7)];
    } else if (gtid < 32768) {            // LT0 = l0_lin2^T
        int j = gtid - 16384;
        LT0[j] = l0_lin2[(j & 127) * H + (j >> 7)];
    } else if (gtid < 49152) {            // LT1 = l1_lin2^T
        int j = gtid - 32768;
        LT1[j] = l1_lin2[(j & 127) * H + (j >> 7)];
    }
    if (gtid < N * EMBED) {               // x gather (blocks 0..127)
        int g = gtid >> 6, c = gtid & 63;
        x[gtid] = emb[ids[g] * EMBED + c];
    }
    {   // lin0: A0 rows for this block's 8 nodes (one output/thread)
        int k = tid & 127, q = tid >> 7;  // q 0..7, wave-uniform
        int nn = __builtin_amdgcn_readfirstlane(n0 + q);
        const float* xr = emb + (size_t)ids[nn] * EMBED;
        const float* wr = l0_lin1 + k * (EMBED + 1);
        float acc = 0.f;
#pragma unroll 4
        for (int c = 0; c < EMBED; c++)
            acc = fmaf(xr[c], wr[c], acc);
        A0[(n0 + q) * H + k] = acc;
    }
    grid_sync(bar, NBLK, b);

    // ---------------- P1: gate0 (8 dsts, 2 waves/dst) + lin1 + A1 ----------------
    {
        int wv = __builtin_amdgcn_readfirstlane(tid >> 6);  // 0..15
        int lane = tid & 63;
        int c0 = 2 * lane;
        int p = wv >> 1, h = wv & 1;
        int dst = n0 + p;

        float xr = wave_sum(x[dst * EMBED + lane] * l0_att_r[lane]);
        float attl0 = l0_att_l[c0], attl1 = l0_att_l[c0 + 1];
        float w0 = l0_lin1[c0 * (EMBED + 1) + EMBED];
        float w1 = l0_lin1[(c0 + 1) * (EMBED + 1) + EMBED];
        int cnt = cursor[dst]; if (cnt > CAP) cnt = CAP;

        float pm_, ps_, pv0, pv1;
        gate_partial(dst, lane, xr, A0, w0, w1, attl0, attl1, srcs, eas, cnt, h * 8,
                     pm_, ps_, pv0, pv1);
        vs[wv * H + c0] = pv0; vs[wv * H + c0 + 1] = pv1;
        if (lane == 0) { pm[wv] = pm_; ps[wv] = ps_; }
        __syncthreads();
        if (h == 0) {
            float o0, o1;
            gate_merge(pm_, ps_, pv0, pv1,
                       pm[wv ^ 1], ps[wv ^ 1], vs[(wv ^ 1) * H + c0], vs[(wv ^ 1) * H + c0 + 1],
                       o0, o1);
            agg[p * H + c0] = o0;
            agg[p * H + c0 + 1] = o1;
        }
        __syncthreads();

        // h1 = relu(agg @ LT0 + b0): one output/thread -> LDS hs (no global h1)
        int k = tid & 127, q = tid >> 7;
        float acc0 = l0_bias[k];
#pragma unroll 2
        for (int ct = 0; ct < H / 4; ct++) {
            float u0 = LT0[(4 * ct + 0) * H + k];
            float u1 = LT0[(4 * ct + 1) * H + k];
            float u2 = LT0[(4 * ct + 2) * H + k];
            float u3 = LT0[(4 * ct + 3) * H + k];
            float4 f0 = *(const float4*)&agg[q * H + 4 * ct];
            acc0 = fmaf(f0.x, u0, acc0); acc0 = fmaf(f0.y, u1, acc0);
            acc0 = fmaf(f0.z, u2, acc0); acc0 = fmaf(f0.w, u3, acc0);
        }
        hs[q * H + k] = fmaxf(acc0, 0.f);
        __syncthreads();

        // A1 = h1 @ WT1 (cross-block operand -> global)
        float a0 = 0.f;
#pragma unroll 2
        for (int ct = 0; ct < H / 4; ct++) {
            float u0 = WT1[(4 * ct + 0) * H + k];
            float u1 = WT1[(4 * ct + 1) * H + k];
            float u2 = WT1[(4 * ct + 2) * H + k];
            float u3 = WT1[(4 * ct + 3) * H + k];
            float4 f0 = *(const float4*)&hs[q * H + 4 * ct];
            a0 = fmaf(f0.x, u0, a0); a0 = fmaf(f0.y, u1, a0);
            a0 = fmaf(f0.z, u2, a0); a0 = fmaf(f0.w, u3, a0);
        }
        A1[(n0 + q) * H + k] = a0;
    }
    grid_sync(bar, 2 * NBLK, b);

    // ---------------- P2: gate1 (8 dsts, 2 waves/dst) + h2 + tail ----------------
    {
        int wv = __builtin_amdgcn_readfirstlane(tid >> 6);
        int lane = tid & 63;
        int c0 = 2 * lane;
        int p = wv >> 1, h = wv & 1;
        int dst = n0 + p;

        float xr = wave_sum(hs[p * H + lane] * l1_att_r[lane] +
                            hs[p * H + 64 + lane] * l1_att_r[64 + lane]);
        float attl0 = l1_att_l[c0], attl1 = l1_att_l[c0 + 1];
        float w0 = l1_lin1[c0 * (H + 1) + H];
        float w1 = l1_lin1[(c0 + 1) * (H + 1) + H];
        int cnt = cursor[dst]; if (cnt > CAP) cnt = CAP;

        float pm_, ps_, pv0, pv1;
        gate_partial(dst, lane, xr, A1, w0, w1, attl0, attl1, srcs, eas, cnt, h * 8,
                     pm_, ps_, pv0, pv1);
        vs[wv * H + c0] = pv0; vs[wv * H + c0 + 1] = pv1;
        if (lane == 0) { pm[wv] = pm_; ps[wv] = ps_; }
        __syncthreads();
        if (h == 0) {
            float o0, o1;
            gate_merge(pm_, ps_, pv0, pv1,
                       pm[wv ^ 1], ps[wv ^ 1], vs[(wv ^ 1) * H + c0], vs[(wv ^ 1) * H + c0 + 1],
                       o0, o1);
            agg[p * H + c0] = o0;
            agg[p * H + c0 + 1] = o1;
        }

        for (int idx = tid; idx < 8 * EMBED; idx += NTHR) {
            int g = idx >> 6, c = idx & 63;
            feat[g * C3 + c] = x[(n0 + g) * EMBED + c];
        }
        for (int idx = tid; idx < 8 * H; idx += NTHR) {
            int g = idx >> 7, c = idx & 127;
            feat[g * C3 + EMBED + c] = hs[g * H + c];
        }
        __syncthreads();

        // h2 = relu(agg @ LT1 + bL1)
        int k = tid & 127, q = tid >> 7;
        float acc0 = l1_bias[k];
#pragma unroll 2
        for (int ct = 0; ct < H / 4; ct++) {
            float u0 = LT1[(4 * ct + 0) * H + k];
            float u1 = LT1[(4 * ct + 1) * H + k];
            float u2 = LT1[(4 * ct + 2) * H + k];
            float u3 = LT1[(4 * ct + 3) * H + k];
            float4 f0 = *(const float4*)&agg[q * H + 4 * ct];
            acc0 = fmaf(f0.x, u0, acc0); acc0 = fmaf(f0.y, u1, acc0);
            acc0 = fmaf(f0.z, u2, acc0); acc0 = fmaf(f0.w, u3, acc0);
        }
        feat[q * C3 + EMBED + H + k] = fmaxf(acc0, 0.f);
        __syncthreads();

        // 320 tail outputs: g*40 + side*20 + t; a-side -> LDS aL, b-side -> global bT
        if (tid < 320) {
            int g = tid / 40, u = tid % 40;
            int t = u % 20, side = u / 20;
            const float* wrow = W1 + t * (2 * C3) + side * C3;
            float s = 0.f;
#pragma unroll 4
            for (int ct = 0; ct < C3 / 4; ct++) {
                float4 fv = *(const float4*)&feat[g * C3 + 4 * ct];
                float4 wv4 = *(const float4*)&wrow[4 * ct];
                s = fmaf(fv.x, wv4.x, s);
                s = fmaf(fv.y, wv4.y, s);
                s = fmaf(fv.z, wv4.z, s);
                s = fmaf(fv.w, wv4.w, s);
            }
            if (side == 0) aL[g * NT + t] = s;
            else bT[t * N + (n0 + g)] = s;
        }
    }
    grid_sync(bar, 3 * NBLK, b);

    // ------- P3: logits + row softmax (8 rows/block; 4 quarters x 2 rows) -------
    {
        float* red = vs;                       // reuse; 8 floats per quarter
        int quarter = tid >> 8;                // 0..3
        int t256 = tid & 255;
        int lg0 = quarter * 2;                 // local row index base (0..6)
        int i0 = n0 + lg0;
        int lane = tid & 63, wvq = (tid >> 6) & 3;
        float* redq = red + quarter * 8;
        float w2r[NT];
#pragma unroll
        for (int t = 0; t < NT; t++) w2r[t] = W2[t];
        float b2v = b2[0];
        float ab[2][NT];
#pragma unroll
        for (int g = 0; g < 2; g++) {
#pragma unroll
            for (int t = 0; t < NT; t++)
                ab[g][t] = aL[(lg0 + g) * NT + t] + b1[t];
        }
        float4 l4[2][2];
        float tmax[2] = {-INFINITY, -INFINITY};
#pragma unroll
        for (int it = 0; it < 2; it++) {
            int j = 4 * t256 + 1024 * it;
            float4 s4[2];
#pragma unroll
            for (int g = 0; g < 2; g++) s4[g] = make_float4(b2v, b2v, b2v, b2v);
#pragma unroll
            for (int t = 0; t < NT; t++) {
                float4 bt4 = *(const float4*)&bT[t * N + j];
#pragma unroll
                for (int g = 0; g < 2; g++) {
                    float a = ab[g][t], w = w2r[t];
                    s4[g].x = fmaf(fmaxf(a + bt4.x, 0.f), w, s4[g].x);
                    s4[g].y = fmaf(fmaxf(a + bt4.y, 0.f), w, s4[g].y);
                    s4[g].z = fmaf(fmaxf(a + bt4.z, 0.f), w, s4[g].z);
                    s4[g].w = fmaf(fmaxf(a + bt4.w, 0.f), w, s4[g].w);
                }
            }
#pragma unroll
            for (int g = 0; g < 2; g++) {
                float4 mm = *(const float4*)&mmat[(size_t)(i0 + g) * N + j];
                s4[g].x *= mm.x; s4[g].y *= mm.y; s4[g].z *= mm.z; s4[g].w *= mm.w;
                l4[g][it] = s4[g];
                tmax[g] = fmaxf(tmax[g], fmaxf(fmaxf(s4[g].x, s4[g].y), fmaxf(s4[g].z, s4[g].w)));
            }
        }
#pragma unroll
        for (int g = 0; g < 2; g++) {
#pragma unroll
            for (int o = 32; o > 0; o >>= 1)
                tmax[g] = fmaxf(tmax[g], __shfl_xor(tmax[g], o, 64));
        }
        if (lane == 0) {
#pragma unroll
            for (int g = 0; g < 2; g++) redq[wvq * 2 + g] = tmax[g];
        }
        __syncthreads();
        float mfin[2];
#pragma unroll
        for (int g = 0; g < 2; g++)
            mfin[g] = fmaxf(fmaxf(redq[g], redq[2 + g]), fmaxf(redq[4 + g], redq[6 + g]));
        __syncthreads();

        float ts[2] = {0.f, 0.f};
#pragma unroll
        for (int it = 0; it < 2; it++) {
#pragma unroll
            for (int g = 0; g < 2; g++) {
                float4 v = l4[g][it];
                v.x = __expf(v.x - mfin[g]);
                v.y = __expf(v.y - mfin[g]);
                v.z = __expf(v.z - mfin[g]);
                v.w = __expf(v.w - mfin[g]);
                l4[g][it] = v;
                ts[g] += v.x + v.y + v.z + v.w;
            }
        }
#pragma unroll
        for (int g = 0; g < 2; g++) {
#pragma unroll
            for (int o = 32; o > 0; o >>= 1) ts[g] += __shfl_xor(ts[g], o, 64);
        }
        if (lane == 0) {
#pragma unroll
            for (int g = 0; g < 2; g++) redq[wvq * 2 + g] = ts[g];
        }
        __syncthreads();
        float inv[2];
#pragma unroll
        for (int g = 0; g < 2; g++)
            inv[g] = 1.f / (redq[g] + redq[2 + g] + redq[4 + g] + redq[6 + g]);

#pragma unroll
        for (int it = 0; it < 2; it++) {
            int j = 4 * t256 + 1024 * it;
#pragma unroll
            for (int g = 0; g < 2; g++) {
                float4 v = l4[g][it];
                v.x *= inv[g]; v.y *= inv[g]; v.z *= inv[g]; v.w *= inv[g];
                *(float4*)&out[(size_t)(i0 + g) * N + j] = v;
            }
        }
    }
}

extern "C" void kernel_launch(void* const* d_in, const int* in_sizes, int n_in,
                              void* d_out, int out_size, void* d_ws, size_t ws_size,
                              hipStream_t stream) {
    const int*   node_ids = (const int*)d_in[0];
    const int*   ei       = (const int*)d_in[1];   // [2][E]: row0 = src, row1 = dst
    const float* eattr    = (const float*)d_in[2];
    const float* mmat     = (const float*)d_in[3];
    const float* emb      = (const float*)d_in[4];
    const float* l0_lin1  = (const float*)d_in[5];
    const float* l0_lin2  = (const float*)d_in[6];
    const float* l0_att_l = (const float*)d_in[7];
    const float* l0_att_r = (const float*)d_in[8];
    const float* l0_bias  = (const float*)d_in[9];
    const float* l1_lin1  = (const float*)d_in[10];
    const float* l1_lin2  = (const float*)d_in[11];
    const float* l1_att_l = (const float*)d_in[12];
    const float* l1_att_r = (const float*)d_in[13];
    const float* l1_bias  = (const float*)d_in[14];
    const float* W1       = (const float*)d_in[15];
    const float* b1       = (const float*)d_in[16];
    const float* W2       = (const float*)d_in[17];
    const float* b2       = (const float*)d_in[18];
    float* out = (float*)d_out;

    char* w = (char*)d_ws;
    auto alloc = [&](size_t bytes) {
        char* p = w;
        w += (bytes + 255) & ~(size_t)255;
        return p;
    };
    int*   cursor = (int*)alloc((N + 512) * sizeof(int));  // cursor[N] + 8 barrier lines
    int*   bar    = cursor + N;
    int*   srcs   = (int*)alloc(N * CAP * sizeof(int));
    float* eas    = (float*)alloc(N * CAP * sizeof(float));
    float* x      = (float*)alloc(N * EMBED * sizeof(float));
    float* A0     = (float*)alloc(N * H * sizeof(float));
    float* A1     = (float*)alloc(N * H * sizeof(float));
    float* bT     = (float*)alloc(NT * N * sizeof(float));
    float* WT1    = (float*)alloc(H * H * sizeof(float));
    float* LT0    = (float*)alloc(H * H * sizeof(float));
    float* LT1    = (float*)alloc(H * H * sizeof(float));

    hipMemsetAsync(cursor, 0, (N + 512) * sizeof(int), stream);

    k_fused<<<NBLK, NTHR, 0, stream>>>(node_ids, ei, eattr, mmat, emb,
                                       l0_lin1, l0_lin2, l0_att_l, l0_att_r, l0_bias,
                                       l1_lin1, l1_lin2, l1_att_l, l1_att_r, l1_bias,
                                       W1, b1, W2, b2,
                                       cursor, bar, srcs, eas, x, A0, A1,
                                       bT, WT1, LT0, LT1, out);
}

// Round 5
// 204.859 us; speedup vs baseline: 2.3831x; 1.0579x over previous
//
#include <hip/hip_runtime.h>
#include <math.h>

#define N 2048
#define E 65536
#define EMBED 64
#define H 128
#define NT 20
#define C3 320   /* EMBED + H + H */
#define CAP 96   /* bucket capacity; Poisson(32) degrees, max ~60 */
#define SLOPE 0.01f
#define NBLK 256
#define NTHR 512

__device__ __forceinline__ float leaky(float x) { return x > 0.f ? x : SLOPE * x; }

__device__ __forceinline__ float wave_sum(float v) {
#pragma unroll
    for (int o = 32; o > 0; o >>= 1) v += __shfl_xor(v, o, 64);
    return v;
}

// Contention-engineered grid barrier for 256 co-resident blocks (proven R4).
// 8 counter cache-lines; poller at s_sleep(32). Release/acquire agent fences
// handle cross-XCD L2 non-coherence.
__device__ __forceinline__ void grid_sync(int* ctr, int target, int b) {
    __syncthreads();
    if (threadIdx.x == 0) {
        __builtin_amdgcn_fence(__ATOMIC_RELEASE, "agent");
        __hip_atomic_fetch_add(&ctr[(b & 7) << 6], 1, __ATOMIC_RELAXED,
                               __HIP_MEMORY_SCOPE_AGENT);
        for (;;) {
            int sum = 0;
#pragma unroll
            for (int i = 0; i < 8; i++)
                sum += __hip_atomic_load(&ctr[i << 6], __ATOMIC_RELAXED,
                                         __HIP_MEMORY_SCOPE_AGENT);
            if (sum >= target) break;
            __builtin_amdgcn_s_sleep(32);
        }
        __builtin_amdgcn_fence(__ATOMIC_ACQUIRE, "agent");
    }
    __syncthreads();
}

// ====== gate: one wave, one dst, 16-edge batches (2x MLP vs batch-8) ======
__device__ __forceinline__ void gate_wave16(
    int base, int lane, float xr,
    const float* __restrict__ A,
    float w0, float w1, float attl0, float attl1,
    const int2* __restrict__ se, int cnt,
    float& out0, float& out1) {
    int c0 = 2 * lane;
    float mmax = -INFINITY, s = 0.f, v0 = 0.f, v1 = 0.f;
    for (int i0 = 0; i0 < cnt; i0 += 16) {
        int nb = cnt - i0; if (nb > 16) nb = 16;
        float h0[16], h1v[16], p[16];
#pragma unroll
        for (int e = 0; e < 16; e++) {
            float ea = 0.f; float2 av = make_float2(0.f, 0.f);
            if (e < nb) {
                int2 v = se[base + i0 + e];
                ea = __int_as_float(v.y);
                av = *(const float2*)&A[v.x * H + c0];
            }
            h0[e] = leaky(fmaf(w0, ea, av.x));
            h1v[e] = leaky(fmaf(w1, ea, av.y));
            p[e] = h0[e] * attl0 + h1v[e] * attl1;
        }
        // 16 independent butterflies
#pragma unroll
        for (int o = 32; o > 0; o >>= 1) {
#pragma unroll
            for (int e = 0; e < 16; e++) p[e] += __shfl_xor(p[e], o, 64);
        }
        float alpha[16];
#pragma unroll
        for (int e = 0; e < 16; e++)
            alpha[e] = (e < nb) ? leaky(p[e] + xr) : -INFINITY;
        float mb = alpha[0];
#pragma unroll
        for (int e = 1; e < 16; e++) mb = fmaxf(mb, alpha[e]);
        float mnew = fmaxf(mmax, mb);
        float scale = __expf(mmax - mnew);  // first batch: exp(-inf)=0
        float sw = 0.f, sv0 = 0.f, sv1 = 0.f;
#pragma unroll
        for (int e = 0; e < 16; e++) {
            float we = __expf(alpha[e] - mnew);  // invalid lanes -> 0
            sw += we;
            sv0 = fmaf(we, h0[e], sv0);
            sv1 = fmaf(we, h1v[e], sv1);
        }
        s = fmaf(s, scale, sw);
        v0 = fmaf(v0, scale, sv0);
        v1 = fmaf(v1, scale, sv1);
        mmax = mnew;
    }
    float inv = 1.f / (s + 1e-16f);
    out0 = v0 * inv;
    out1 = v1 * inv;
}

// ===== fused kernel: 256 blocks x 512 threads (1 block/CU), 3 grid barriers =====
// Block b owns nodes 8b..8b+7 in every phase; x/h1/a-side live in LDS only.
// P3 logits staged in LDS (64 KB) to keep VGPRs low WITHOUT spilling (R4 bug).
__global__ __launch_bounds__(NTHR) void k_fused(
    const int* __restrict__ ids, const int* __restrict__ ei,
    const float* __restrict__ eattr, const float* __restrict__ mmat,
    const float* __restrict__ emb,
    const float* __restrict__ l0_lin1, const float* __restrict__ l0_lin2,
    const float* __restrict__ l0_att_l, const float* __restrict__ l0_att_r,
    const float* __restrict__ l0_bias,
    const float* __restrict__ l1_lin1, const float* __restrict__ l1_lin2,
    const float* __restrict__ l1_att_l, const float* __restrict__ l1_att_r,
    const float* __restrict__ l1_bias,
    const float* __restrict__ W1, const float* __restrict__ b1,
    const float* __restrict__ W2, const float* __restrict__ b2,
    int* __restrict__ cursor, int* __restrict__ bar,
    int2* __restrict__ se,
    float* __restrict__ A0, float* __restrict__ A1,
    float* __restrict__ bT,
    float* __restrict__ WT1, float* __restrict__ LT0, float* __restrict__ LT1,
    float* __restrict__ out) {
    // LDS (floats): xL[8][64] | agg[8][128] | hs[8][128] | feat[8][320] |
    //               aL[8][20] | Lrow[8][2048] | redM[64] | redS[64]
    __shared__ float smem[512 + 1024 + 1024 + 2560 + 160 + 16384 + 64 + 64];
    float* xL   = smem;                  // 512
    float* agg  = smem + 512;            // 1024
    float* hs   = smem + 1536;           // 1024
    float* feat = smem + 2560;           // 2560
    float* aL   = smem + 5120;           // 160
    float* Lrow = smem + 5280;           // 16384
    float* redM = smem + 21664;          // 64
    float* redS = smem + 21728;          // 64
    const int b = blockIdx.x;
    const int tid = threadIdx.x;
    const int gtid = b * NTHR + tid;     // 0..131071
    const int n0 = b * 8;

    // ---------------- P0: scatter + transposes + xL + A0 ----------------
    if (gtid < E) {                       // scatter (blocks 0..127)
        int d = ei[E + gtid];
        int pos = atomicAdd(&cursor[d], 1);
        if (pos < CAP)
            se[d * CAP + pos] = make_int2(ei[gtid], __float_as_int(eattr[gtid]));
    } else {                              // transposes (blocks 128..223)
        int j = gtid - E;
        if (j < 16384) {                  // WT1 = l1_lin1[:, :H]^T
            WT1[j] = l1_lin1[(j & 127) * (H + 1) + (j >> 7)];
        } else if (j < 32768) {           // LT0 = l0_lin2^T
            int jj = j - 16384;
            LT0[jj] = l0_lin2[(jj & 127) * H + (jj >> 7)];
        } else if (j < 49152) {           // LT1 = l1_lin2^T
            int jj = j - 32768;
            LT1[jj] = l1_lin2[(jj & 127) * H + (jj >> 7)];
        }
    }
    {   // xL: one element per thread (8 nodes x 64 ch == 512)
        int g = tid >> 6, c = tid & 63;
        xL[g * EMBED + c] = emb[ids[n0 + g] * EMBED + c];
    }
    __syncthreads();
    {   // lin0: A0 rows for this block's 8 nodes; 2 outputs/thread
        int k = tid & 127, q = tid >> 7;  // q 0..3 -> nodes q, q+4
        const float* wr = l0_lin1 + k * (EMBED + 1);
        float accA = 0.f, accB = 0.f;
#pragma unroll 4
        for (int c = 0; c < EMBED; c++) {
            float w = wr[c];
            accA = fmaf(xL[q * EMBED + c], w, accA);
            accB = fmaf(xL[(q + 4) * EMBED + c], w, accB);
        }
        A0[(n0 + q) * H + k] = accA;
        A0[(n0 + q + 4) * H + k] = accB;
    }
    grid_sync(bar, NBLK, b);

    // ---------------- P1: gate0 (8 dsts, 1 wave/dst, batch-16) + lin1 + A1 ----------------
    {
        int wv = __builtin_amdgcn_readfirstlane(tid >> 6);  // 0..7
        int lane = tid & 63;
        int c0 = 2 * lane;
        int dst = n0 + wv;

        float xr = wave_sum(xL[wv * EMBED + lane] * l0_att_r[lane]);
        float attl0 = l0_att_l[c0], attl1 = l0_att_l[c0 + 1];
        float w0 = l0_lin1[c0 * (EMBED + 1) + EMBED];
        float w1 = l0_lin1[(c0 + 1) * (EMBED + 1) + EMBED];
        int cnt = cursor[dst]; if (cnt > CAP) cnt = CAP;

        float o0, o1;
        gate_wave16(dst * CAP, lane, xr, A0, w0, w1, attl0, attl1, se, cnt, o0, o1);
        agg[wv * H + c0] = o0;
        agg[wv * H + c0 + 1] = o1;
        __syncthreads();

        // h1 = relu(agg @ LT0 + b0): 2 outputs/thread -> hs (LDS only)
        int k = tid & 127, q = tid >> 7;
        float bk = l0_bias[k];
        float acc0 = bk, acc1 = bk;
#pragma unroll 2
        for (int ct = 0; ct < H / 4; ct++) {
            float u0 = LT0[(4 * ct + 0) * H + k];
            float u1 = LT0[(4 * ct + 1) * H + k];
            float u2 = LT0[(4 * ct + 2) * H + k];
            float u3 = LT0[(4 * ct + 3) * H + k];
            float4 f0 = *(const float4*)&agg[q * H + 4 * ct];
            float4 f1 = *(const float4*)&agg[(q + 4) * H + 4 * ct];
            acc0 = fmaf(f0.x, u0, acc0); acc0 = fmaf(f0.y, u1, acc0);
            acc0 = fmaf(f0.z, u2, acc0); acc0 = fmaf(f0.w, u3, acc0);
            acc1 = fmaf(f1.x, u0, acc1); acc1 = fmaf(f1.y, u1, acc1);
            acc1 = fmaf(f1.z, u2, acc1); acc1 = fmaf(f1.w, u3, acc1);
        }
        hs[q * H + k] = fmaxf(acc0, 0.f);
        hs[(q + 4) * H + k] = fmaxf(acc1, 0.f);
        __syncthreads();

        // A1 = h1 @ WT1 (cross-block operand -> global)
        float a0 = 0.f, a1 = 0.f;
#pragma unroll 2
        for (int ct = 0; ct < H / 4; ct++) {
            float u0 = WT1[(4 * ct + 0) * H + k];
            float u1 = WT1[(4 * ct + 1) * H + k];
            float u2 = WT1[(4 * ct + 2) * H + k];
            float u3 = WT1[(4 * ct + 3) * H + k];
            float4 f0 = *(const float4*)&hs[q * H + 4 * ct];
            float4 f1 = *(const float4*)&hs[(q + 4) * H + 4 * ct];
            a0 = fmaf(f0.x, u0, a0); a0 = fmaf(f0.y, u1, a0);
            a0 = fmaf(f0.z, u2, a0); a0 = fmaf(f0.w, u3, a0);
            a1 = fmaf(f1.x, u0, a1); a1 = fmaf(f1.y, u1, a1);
            a1 = fmaf(f1.z, u2, a1); a1 = fmaf(f1.w, u3, a1);
        }
        A1[(n0 + q) * H + k] = a0;
        A1[(n0 + q + 4) * H + k] = a1;
    }
    grid_sync(bar, 2 * NBLK, b);

    // ---------------- P2: gate1 (batch-16) + h2 + tail ----------------
    {
        int wv = __builtin_amdgcn_readfirstlane(tid >> 6);
        int lane = tid & 63;
        int c0 = 2 * lane;
        int dst = n0 + wv;

        float xr = wave_sum(hs[wv * H + lane] * l1_att_r[lane] +
                            hs[wv * H + 64 + lane] * l1_att_r[64 + lane]);
        float attl0 = l1_att_l[c0], attl1 = l1_att_l[c0 + 1];
        float w0 = l1_lin1[c0 * (H + 1) + H];
        float w1 = l1_lin1[(c0 + 1) * (H + 1) + H];
        int cnt = cursor[dst]; if (cnt > CAP) cnt = CAP;

        float o0, o1;
        gate_wave16(dst * CAP, lane, xr, A1, w0, w1, attl0, attl1, se, cnt, o0, o1);
        agg[wv * H + c0] = o0;
        agg[wv * H + c0 + 1] = o1;

        // feat = [x | h1 | h2]
        for (int idx = tid; idx < 8 * EMBED; idx += NTHR) {
            int g = idx >> 6, c = idx & 63;
            feat[g * C3 + c] = xL[g * EMBED + c];
        }
        for (int idx = tid; idx < 8 * H; idx += NTHR) {
            int g = idx >> 7, c = idx & 127;
            feat[g * C3 + EMBED + c] = hs[g * H + c];
        }
        __syncthreads();

        // h2 = relu(agg @ LT1 + bL1): 2 outputs/thread
        int k = tid & 127, q = tid >> 7;
        float bk = l1_bias[k];
        float acc0 = bk, acc1 = bk;
#pragma unroll 2
        for (int ct = 0; ct < H / 4; ct++) {
            float u0 = LT1[(4 * ct + 0) * H + k];
            float u1 = LT1[(4 * ct + 1) * H + k];
            float u2 = LT1[(4 * ct + 2) * H + k];
            float u3 = LT1[(4 * ct + 3) * H + k];
            float4 f0 = *(const float4*)&agg[q * H + 4 * ct];
            float4 f1 = *(const float4*)&agg[(q + 4) * H + 4 * ct];
            acc0 = fmaf(f0.x, u0, acc0); acc0 = fmaf(f0.y, u1, acc0);
            acc0 = fmaf(f0.z, u2, acc0); acc0 = fmaf(f0.w, u3, acc0);
            acc1 = fmaf(f1.x, u0, acc1); acc1 = fmaf(f1.y, u1, acc1);
            acc1 = fmaf(f1.z, u2, acc1); acc1 = fmaf(f1.w, u3, acc1);
        }
        feat[q * C3 + EMBED + H + k] = fmaxf(acc0, 0.f);
        feat[(q + 4) * C3 + EMBED + H + k] = fmaxf(acc1, 0.f);
        __syncthreads();

        // 320 tail outputs: a-side -> LDS aL (b1 folded in), b-side -> global bT
        if (tid < 320) {
            int g = tid / 40, u = tid % 40;
            int t = u % 20, side = u / 20;
            const float* wrow = W1 + t * (2 * C3) + side * C3;
            float s = 0.f;
#pragma unroll 4
            for (int ct = 0; ct < C3 / 4; ct++) {
                float4 fv = *(const float4*)&feat[g * C3 + 4 * ct];
                float4 wv4 = *(const float4*)&wrow[4 * ct];
                s = fmaf(fv.x, wv4.x, s);
                s = fmaf(fv.y, wv4.y, s);
                s = fmaf(fv.z, wv4.z, s);
                s = fmaf(fv.w, wv4.w, s);
            }
            if (side == 0) aL[g * NT + t] = s + b1[t];
            else bT[t * N + (n0 + g)] = s;
        }
    }
    grid_sync(bar, 3 * NBLK, b);

    // ------- P3: logits via LDS staging + row softmax (8 rows/block) -------
    {
        int lane = tid & 63, wv = tid >> 6;  // wv 0..7
        int j = 4 * tid;                     // 512 threads x 4 = 2048 cols
        float w2r[NT];
#pragma unroll
        for (int t = 0; t < NT; t++) w2r[t] = W2[t];
        float b2v = b2[0];
        float4 bt4[NT];
#pragma unroll
        for (int t = 0; t < NT; t++) bt4[t] = *(const float4*)&bT[t * N + j];

        // pass 1: logits -> Lrow; per-row max partials -> redM
#pragma unroll
        for (int g = 0; g < 8; g++) {
            float4 s4 = make_float4(b2v, b2v, b2v, b2v);
#pragma unroll
            for (int t = 0; t < NT; t++) {
                float a = aL[g * NT + t];
                float w = w2r[t];
                s4.x = fmaf(fmaxf(a + bt4[t].x, 0.f), w, s4.x);
                s4.y = fmaf(fmaxf(a + bt4[t].y, 0.f), w, s4.y);
                s4.z = fmaf(fmaxf(a + bt4[t].z, 0.f), w, s4.z);
                s4.w = fmaf(fmaxf(a + bt4[t].w, 0.f), w, s4.w);
            }
            float4 mm = *(const float4*)&mmat[(size_t)(n0 + g) * N + j];
            s4.x *= mm.x; s4.y *= mm.y; s4.z *= mm.z; s4.w *= mm.w;
            *(float4*)&Lrow[g * 2048 + j] = s4;
            float tm = fmaxf(fmaxf(s4.x, s4.y), fmaxf(s4.z, s4.w));
#pragma unroll
            for (int o = 32; o > 0; o >>= 1) tm = fmaxf(tm, __shfl_xor(tm, o, 64));
            if (lane == 0) redM[g * 8 + wv] = tm;
        }
        __syncthreads();
        float mfin[8];
#pragma unroll
        for (int g = 0; g < 8; g++) {
            float m = redM[g * 8 + 0];
#pragma unroll
            for (int w = 1; w < 8; w++) m = fmaxf(m, redM[g * 8 + w]);
            mfin[g] = m;
        }
        // pass 2: exp-sum partials -> redS
#pragma unroll
        for (int g = 0; g < 8; g++) {
            float4 v = *(const float4*)&Lrow[g * 2048 + j];
            float ts = __expf(v.x - mfin[g]) + __expf(v.y - mfin[g]) +
                       __expf(v.z - mfin[g]) + __expf(v.w - mfin[g]);
#pragma unroll
            for (int o = 32; o > 0; o >>= 1) ts += __shfl_xor(ts, o, 64);
            if (lane == 0) redS[g * 8 + wv] = ts;
        }
        __syncthreads();
        // pass 3: normalize + write
#pragma unroll
        for (int g = 0; g < 8; g++) {
            float s = 0.f;
#pragma unroll
            for (int w = 0; w < 8; w++) s += redS[g * 8 + w];
            float inv = 1.f / s;
            float4 v = *(const float4*)&Lrow[g * 2048 + j];
            float4 o4;
            o4.x = __expf(v.x - mfin[g]) * inv;
            o4.y = __expf(v.y - mfin[g]) * inv;
            o4.z = __expf(v.z - mfin[g]) * inv;
            o4.w = __expf(v.w - mfin[g]) * inv;
            *(float4*)&out[(size_t)(n0 + g) * N + j] = o4;
        }
    }
}

extern "C" void kernel_launch(void* const* d_in, const int* in_sizes, int n_in,
                              void* d_out, int out_size, void* d_ws, size_t ws_size,
                              hipStream_t stream) {
    const int*   node_ids = (const int*)d_in[0];
    const int*   ei       = (const int*)d_in[1];   // [2][E]: row0 = src, row1 = dst
    const float* eattr    = (const float*)d_in[2];
    const float* mmat     = (const float*)d_in[3];
    const float* emb      = (const float*)d_in[4];
    const float* l0_lin1  = (const float*)d_in[5];
    const float* l0_lin2  = (const float*)d_in[6];
    const float* l0_att_l = (const float*)d_in[7];
    const float* l0_att_r = (const float*)d_in[8];
    const float* l0_bias  = (const float*)d_in[9];
    const float* l1_lin1  = (const float*)d_in[10];
    const float* l1_lin2  = (const float*)d_in[11];
    const float* l1_att_l = (const float*)d_in[12];
    const float* l1_att_r = (const float*)d_in[13];
    const float* l1_bias  = (const float*)d_in[14];
    const float* W1       = (const float*)d_in[15];
    const float* b1       = (const float*)d_in[16];
    const float* W2       = (const float*)d_in[17];
    const float* b2       = (const float*)d_in[18];
    float* out = (float*)d_out;

    char* w = (char*)d_ws;
    auto alloc = [&](size_t bytes) {
        char* p = w;
        w += (bytes + 255) & ~(size_t)255;
        return p;
    };
    int*   cursor = (int*)alloc((N + 512) * sizeof(int));  // cursor[N] + 8 barrier lines
    int*   bar    = cursor + N;
    int2*  se     = (int2*)alloc(N * CAP * sizeof(int2));
    float* A0     = (float*)alloc(N * H * sizeof(float));
    float* A1     = (float*)alloc(N * H * sizeof(float));
    float* bT     = (float*)alloc(NT * N * sizeof(float));
    float* WT1    = (float*)alloc(H * H * sizeof(float));
    float* LT0    = (float*)alloc(H * H * sizeof(float));
    float* LT1    = (float*)alloc(H * H * sizeof(float));

    hipMemsetAsync(cursor, 0, (N + 512) * sizeof(int), stream);

    k_fused<<<NBLK, NTHR, 0, stream>>>(node_ids, ei, eattr, mmat, emb,
                                       l0_lin1, l0_lin2, l0_att_l, l0_att_r, l0_bias,
                                       l1_lin1, l1_lin2, l1_att_l, l1_att_r, l1_bias,
                                       W1, b1, W2, b2,
                                       cursor, bar, se, A0, A1,
                                       bT, WT1, LT0, LT1, out);
}